// Round 4
// baseline (158.089 us; speedup 1.0000x reference)
//
#include <hip/hip_runtime.h>
#include <hip/hip_bf16.h>

#define LEAK 0.2f

typedef __attribute__((ext_vector_type(8))) short short8;
typedef __attribute__((ext_vector_type(4))) float f32x4;

__device__ __forceinline__ float bf2f(unsigned short u) {
  union { unsigned v; float f; } c;
  c.v = ((unsigned)u) << 16;
  return c.f;
}

// async global->LDS, 16B per lane. LDS dest = wave-uniform base + lane*16 (HW scatter).
__device__ __forceinline__ void gll16(const void* g, void* l) {
  __builtin_amdgcn_global_load_lds((const __attribute__((address_space(1))) void*)g,
                                   (__attribute__((address_space(3))) void*)l, 16, 0, 0);
}

// ---------- fused prep: x->bf16 convert ++ W1,W2 transpose+convert ----------
// grid: [0,6144) convert, [6144,7680) W1t, [7680,7808) W2t
__global__ __launch_bounds__(256) void k_prep(const float* __restrict__ x,
                                              __hip_bfloat16* __restrict__ xb,
                                              const float* __restrict__ W1,
                                              __hip_bfloat16* __restrict__ W1t,
                                              const float* __restrict__ W2,
                                              __hip_bfloat16* __restrict__ W2t) {
  int b = blockIdx.x;
  int t = threadIdx.x;
  if (b < 6144) {
    int idx = b * 256 + t;
    float4 v = reinterpret_cast<const float4*>(x)[idx];
    union { ushort4 u; __hip_bfloat16 h[4]; } c;
    c.h[0] = __float2bfloat16(v.x);
    c.h[1] = __float2bfloat16(v.y);
    c.h[2] = __float2bfloat16(v.z);
    c.h[3] = __float2bfloat16(v.w);
    reinterpret_cast<ushort4*>(xb)[idx] = c.u;
    return;
  }
  __shared__ float tile[32][33];
  const float* W;
  __hip_bfloat16* Wt;
  int K, N, kblk, nblk;
  if (b < 7680) {
    int bb = b - 6144;              // W1: 3072x512 -> 512x3072, grid 96x16
    W = W1; Wt = W1t; K = 3072; N = 512;
    kblk = bb % 96; nblk = bb / 96;
  } else {
    int bb = b - 7680;              // W2: 512x256 -> 256x512, grid 16x8
    W = W2; Wt = W2t; K = 512; N = 256;
    kblk = bb % 16; nblk = bb / 16;
  }
  int k0 = kblk * 32, n0 = nblk * 32;
  int tx = t & 31, ty = t >> 5;  // 32 x 8
#pragma unroll
  for (int r = 0; r < 4; ++r)
    tile[ty + r * 8][tx] = W[(long)(k0 + ty + r * 8) * N + n0 + tx];
  __syncthreads();
#pragma unroll
  for (int r = 0; r < 4; ++r)
    Wt[(long)(n0 + ty + r * 8) * K + k0 + tx] = __float2bfloat16(tile[tx][ty + r * 8]);
}

// ---------- bf16 MFMA GEMM, global_load_lds staging + LDS double-buffer ----------
// Block tile (32*TM)x(32*TN), BK=32, 4 waves 2x2, wave tile (16*TM)x(16*TN).
// FUSE: split-K=1, epilogue bias+leaky -> bf16. else: store fp32 partial per z.
template <int TM, int TN, bool FUSE>
__global__ __launch_bounds__(256) void k_gemm(const __hip_bfloat16* __restrict__ A,
                                              const __hip_bfloat16* __restrict__ Bt,
                                              const float* __restrict__ bias,
                                              float* __restrict__ Cp,
                                              __hip_bfloat16* __restrict__ Cb,
                                              int M, int N, int K, int KSPL) {
  constexpr int BM = 32 * TM, BN = 32 * TN;
  constexpr int CA = BM / 64, CB = BN / 64;  // gll calls per wave (16 rows each)
  __shared__ __align__(16) __hip_bfloat16 As[2][BM * 32];  // rows of 32, contiguous (gll)
  __shared__ __align__(16) __hip_bfloat16 Bs[2][BN * 32];
  int tid = threadIdx.x;
  int lane = tid & 63;
  int wv = tid >> 6;
  int wm = wv & 1, wn = wv >> 1;
  int quad = lane >> 4, l16 = lane & 15;
  long m0 = (long)blockIdx.x * BM, n0 = (long)blockIdx.y * BN;
  int kStart = blockIdx.z * KSPL;
  int lrow = lane >> 2, lcol = (lane & 3) * 8;

  const __hip_bfloat16* Ap[CA];
  const __hip_bfloat16* Bp[CB];
#pragma unroll
  for (int c = 0; c < CA; ++c)
    Ap[c] = A + (m0 + (wv * CA + c) * 16 + lrow) * (long)K + kStart + lcol;
#pragma unroll
  for (int c = 0; c < CB; ++c)
    Bp[c] = Bt + (n0 + (wv * CB + c) * 16 + lrow) * (long)K + kStart + lcol;

  auto stage = [&](int buf, int kb) {
#pragma unroll
    for (int c = 0; c < CA; ++c)
      gll16(Ap[c] + kb, &As[buf][(wv * CA + c) * 512]);  // base wave-uniform; HW adds lane*16B
#pragma unroll
    for (int c = 0; c < CB; ++c)
      gll16(Bp[c] + kb, &Bs[buf][(wv * CB + c) * 512]);
  };

  f32x4 acc[TM][TN] = {};
  stage(0, 0);
  int nIter = KSPL >> 5;
  for (int it = 0; it < nIter; ++it) {
    __syncthreads();  // drains vmcnt: buf 'it&1' is ready; prev reads done
    if (it + 1 < nIter) stage((it + 1) & 1, (it + 1) * 32);
    int buf = it & 1;
    short8 af[TM], bfg[TN];
#pragma unroll
    for (int t = 0; t < TM; ++t)
      af[t] = *reinterpret_cast<const short8*>(&As[buf][(wm * 16 * TM + t * 16 + l16) * 32 + quad * 8]);
#pragma unroll
    for (int u = 0; u < TN; ++u)
      bfg[u] = *reinterpret_cast<const short8*>(&Bs[buf][(wn * 16 * TN + u * 16 + l16) * 32 + quad * 8]);
#pragma unroll
    for (int t = 0; t < TM; ++t)
#pragma unroll
      for (int u = 0; u < TN; ++u)
        acc[t][u] = __builtin_amdgcn_mfma_f32_16x16x32_bf16(af[t], bfg[u], acc[t][u], 0, 0, 0);
  }

  if (FUSE) {
#pragma unroll
    for (int t = 0; t < TM; ++t)
#pragma unroll
      for (int u = 0; u < TN; ++u)
#pragma unroll
        for (int r = 0; r < 4; ++r) {
          long gm = m0 + wm * 16 * TM + t * 16 + quad * 4 + r;
          long gn = n0 + wn * 16 * TN + u * 16 + l16;
          float v = acc[t][u][r] + bias[gn];
          v = v > 0.f ? v : LEAK * v;
          Cb[gm * N + gn] = __float2bfloat16(v);
        }
  } else {
    float* Cz = Cp + (long)blockIdx.z * M * N;
#pragma unroll
    for (int t = 0; t < TM; ++t)
#pragma unroll
      for (int u = 0; u < TN; ++u)
#pragma unroll
        for (int r = 0; r < 4; ++r) {
          long gm = m0 + wm * 16 * TM + t * 16 + quad * 4 + r;
          long gn = n0 + wn * 16 * TN + u * 16 + l16;
          Cz[gm * N + gn] = acc[t][u][r];
        }
  }
}

// ---------- combine NZ partials + bias + leakyrelu -> bf16 ----------
template <int NZ>
__global__ __launch_bounds__(256) void k_comb(const float* __restrict__ P,
                                              const float* __restrict__ bias,
                                              __hip_bfloat16* __restrict__ Ob,
                                              int total4, int nmask) {
  int idx = blockIdx.x * 256 + threadIdx.x;
  if (idx >= total4) return;
  float4 v = reinterpret_cast<const float4*>(P)[idx];
#pragma unroll
  for (int z = 1; z < NZ; ++z) {
    float4 a = reinterpret_cast<const float4*>(P + (long)z * total4 * 4)[idx];
    v.x += a.x; v.y += a.y; v.z += a.z; v.w += a.w;
  }
  int col = (idx * 4) & nmask;
  float4 bs = *reinterpret_cast<const float4*>(bias + col);
  v.x += bs.x; v.y += bs.y; v.z += bs.z; v.w += bs.w;
  v.x = v.x > 0.f ? v.x : LEAK * v.x;
  v.y = v.y > 0.f ? v.y : LEAK * v.y;
  v.z = v.z > 0.f ? v.z : LEAK * v.z;
  v.w = v.w > 0.f ? v.w : LEAK * v.w;
  union { ushort4 u; __hip_bfloat16 h[4]; } c;
  c.h[0] = __float2bfloat16(v.x);
  c.h[1] = __float2bfloat16(v.y);
  c.h[2] = __float2bfloat16(v.z);
  c.h[3] = __float2bfloat16(v.w);
  reinterpret_cast<ushort4*>(Ob)[idx] = c.u;
}

// ---------- per-feature GEMV (m = h2 @ T[:,f]) + bucketed features, O(B) ----------
// feats[i] = sum_j e^{-|mi-mj|} via 256 value buckets (lower buckets: n_i*sum(p),
// upper: p_i*sum(n) -- exact by monotonicity; own bucket exact pairwise).
__global__ __launch_bounds__(1024) void k_feats(const __hip_bfloat16* __restrict__ h2b,
                                                const float* __restrict__ T,
                                                float* __restrict__ featsT) {
  __shared__ float Tcol[256];
  __shared__ float sP[2048], sN[2048];
  __shared__ float Sp[2048], Sn[2048];
  __shared__ int Smeta[2048];
  __shared__ short sB[2048];
  __shared__ int cnt[256], bstart[256], bcur[256];
  __shared__ float bsP[256], bsN[256], Pbel[256], Nab[256];
  __shared__ float wred[32];
  __shared__ float sMin, sMax;
  int f = blockIdx.x;
  int t = threadIdx.x;
  int lane = t & 63, wv = t >> 6;

  if (t < 256) Tcol[t] = T[t * 100 + f];
  if (t < 256) cnt[t] = 0;
  __syncthreads();

  // GEMV: m[e] = sum_c h2[e][c] * T[c][f]
  float m[2];
  float lmin = 3.4e38f, lmax = -3.4e38f;
#pragma unroll
  for (int r = 0; r < 2; ++r) {
    int e = t + r * 1024;
    const short8* hp = reinterpret_cast<const short8*>(h2b + (long)e * 256);
    float acc = 0.f;
#pragma unroll 4
    for (int c8 = 0; c8 < 32; ++c8) {
      short8 hv = hp[c8];
#pragma unroll
      for (int j = 0; j < 8; ++j)
        acc += bf2f((unsigned short)hv[j]) * Tcol[c8 * 8 + j];
    }
    m[r] = acc;
    lmin = fminf(lmin, acc);
    lmax = fmaxf(lmax, acc);
  }
#pragma unroll
  for (int d = 32; d; d >>= 1) {
    lmin = fminf(lmin, __shfl_down(lmin, d));
    lmax = fmaxf(lmax, __shfl_down(lmax, d));
  }
  if (lane == 0) { wred[wv] = lmin; wred[16 + wv] = lmax; }
  __syncthreads();
  if (t == 0) {
    float a = wred[0], b = wred[16];
    for (int i = 1; i < 16; ++i) { a = fminf(a, wred[i]); b = fmaxf(b, wred[16 + i]); }
    sMin = a; sMax = b;
  }
  __syncthreads();
  float mn = sMin, mx = sMax;
  float rge = mx - mn;
  float scale = (rge > 1e-20f) ? 255.0f / rge : 0.f;
  float mid = 0.5f * (mn + mx);
#pragma unroll
  for (int r = 0; r < 2; ++r) {
    int e = t + r * 1024;
    float v = m[r];
    int b = (int)((v - mn) * scale);
    b = b < 255 ? b : 255;
    float arg = fminf(fmaxf(v - mid, -60.f), 60.f);
    sP[e] = __expf(arg);
    sN[e] = __expf(-arg);
    sB[e] = (short)b;
    atomicAdd(&cnt[b], 1);
  }
  __syncthreads();
  if (wv == 0) {  // exclusive prefix of cnt (4 bins/lane + wave scan)
    int b4 = lane * 4;
    int c0 = cnt[b4], c1 = cnt[b4 + 1], c2 = cnt[b4 + 2], c3 = cnt[b4 + 3];
    int tot = c0 + c1 + c2 + c3;
    int inc = tot;
#pragma unroll
    for (int d = 1; d < 64; d <<= 1) {
      int y = __shfl_up(inc, d);
      if (lane >= d) inc += y;
    }
    int run = inc - tot;
    bstart[b4] = run; bcur[b4] = run; run += c0;
    bstart[b4 + 1] = run; bcur[b4 + 1] = run; run += c1;
    bstart[b4 + 2] = run; bcur[b4 + 2] = run; run += c2;
    bstart[b4 + 3] = run; bcur[b4 + 3] = run;
  }
  __syncthreads();
#pragma unroll
  for (int r = 0; r < 2; ++r) {  // scatter to bucket order
    int e = t + r * 1024;
    int b = sB[e];
    int slot = atomicAdd(&bcur[b], 1);
    Sp[slot] = sP[e];
    Sn[slot] = sN[e];
    Smeta[slot] = (b << 16) | e;
  }
  __syncthreads();
  if (t < 256) {  // per-bucket sums
    int s0 = bstart[t], s1 = s0 + cnt[t];
    float ap = 0.f, an = 0.f;
    for (int q = s0; q < s1; ++q) { ap += Sp[q]; an += Sn[q]; }
    bsP[t] = ap; bsN[t] = an;
  }
  __syncthreads();
  if (wv == 0) {  // bucket-level exclusive prefix(P) / suffix(N)
    int b4 = lane * 4;
    float p0 = bsP[b4], p1 = bsP[b4 + 1], p2 = bsP[b4 + 2], p3 = bsP[b4 + 3];
    float n0 = bsN[b4], n1 = bsN[b4 + 1], n2 = bsN[b4 + 2], n3 = bsN[b4 + 3];
    float tp = p0 + p1 + p2 + p3, tn = n0 + n1 + n2 + n3;
    float ip = tp, in_ = tn;
#pragma unroll
    for (int d = 1; d < 64; d <<= 1) {
      float yp = __shfl_up(ip, d);
      float yn = __shfl_up(in_, d);
      if (lane >= d) { ip += yp; in_ += yn; }
    }
    float totn = __shfl(in_, 63);
    float runp = ip - tp;
    float runn = in_ - tn;
    Pbel[b4] = runp; Nab[b4] = totn - runn - n0; runp += p0; runn += n0;
    Pbel[b4 + 1] = runp; Nab[b4 + 1] = totn - runn - n1; runp += p1; runn += n1;
    Pbel[b4 + 2] = runp; Nab[b4 + 2] = totn - runn - n2; runp += p2; runn += n2;
    Pbel[b4 + 3] = runp; Nab[b4 + 3] = totn - runn - n3;
  }
  __syncthreads();
#pragma unroll
  for (int r = 0; r < 2; ++r) {
    int s = t + r * 1024;
    int meta = Smeta[s];
    int b = meta >> 16;
    int idx = meta & 0xFFFF;
    float p = Sp[s], n = Sn[s];
    float acc = n * Pbel[b] + p * Nab[b];
    int q0 = bstart[b], q1 = q0 + cnt[b];
    for (int q = q0; q < q1; ++q) acc += fminf(p * Sn[q], n * Sp[q]);
    featsT[(long)f * 2048 + idx] = acc;
  }
}

// ---------- final: out[i] = h2[i,:].Wf[0:256] + featsT[:,i].Wf[256:356] + bf ----------
__global__ __launch_bounds__(256) void k_final(const __hip_bfloat16* __restrict__ h2b,
                                               const float* __restrict__ featsT,
                                               const float* __restrict__ Wf,
                                               const float* __restrict__ bfp,
                                               float* __restrict__ out) {
  int wv = threadIdx.x >> 6, lane = threadIdx.x & 63;
  long i = (long)blockIdx.x * 4 + wv;
  const unsigned short* hrow = reinterpret_cast<const unsigned short*>(h2b) + i * 256;
  float s = 0.f;
#pragma unroll
  for (int c = lane; c < 256; c += 64) s += bf2f(hrow[c]) * Wf[c];
  for (int f = lane; f < 100; f += 64) s += featsT[(long)f * 2048 + i] * Wf[256 + f];
#pragma unroll
  for (int off = 32; off; off >>= 1) s += __shfl_down(s, off);
  if (lane == 0) out[i] = s + bfp[0];
}

extern "C" void kernel_launch(void* const* d_in, const int* in_sizes, int n_in,
                              void* d_out, int out_size, void* d_ws, size_t ws_size,
                              hipStream_t stream) {
  const float* x  = (const float*)d_in[0];
  const float* W1 = (const float*)d_in[1];
  const float* b1 = (const float*)d_in[2];
  const float* W2 = (const float*)d_in[3];
  const float* b2 = (const float*)d_in[4];
  const float* T  = (const float*)d_in[5];
  const float* Wf = (const float*)d_in[6];
  const float* bf = (const float*)d_in[7];
  float* out = (float*)d_out;

  char* w = (char*)d_ws;
  auto alloc = [&](size_t b) { char* p = w; w += (b + 255) & ~(size_t)255; return p; };
  __hip_bfloat16* xb  = (__hip_bfloat16*)alloc(2048L * 3072 * 2);  // 12 MB
  __hip_bfloat16* W1t = (__hip_bfloat16*)alloc(512L * 3072 * 2);   // 3 MB
  __hip_bfloat16* W2t = (__hip_bfloat16*)alloc(256L * 512 * 2);
  __hip_bfloat16* h1b = (__hip_bfloat16*)alloc(2048L * 512 * 2);   // 2 MB
  __hip_bfloat16* h2b = (__hip_bfloat16*)alloc(2048L * 256 * 2);   // 1 MB
  float*          feT = (float*)alloc(100L * 2048 * 4);            // 0.8 MB
  float*          P1  = (float*)alloc(4L * 2048 * 512 * 4);        // 16 MB

  // prep: x->bf16 (6144 blocks) + W1t (1536) + W2t (128)
  k_prep<<<7808, 256, 0, stream>>>(x, xb, W1, W1t, W2, W2t);
  // h1: 128x128 tiles, split-K=4 (256 blocks), gll+dbuf
  k_gemm<4, 4, false><<<dim3(16, 4, 4), 256, 0, stream>>>(
      xb, W1t, nullptr, P1, nullptr, 2048, 512, 3072, 768);
  k_comb<4><<<1024, 256, 0, stream>>>(P1, b1, h1b, 262144, 511);
  // h2: 64x64 tiles, split-K=1, fused bias+leaky -> bf16
  k_gemm<2, 2, true><<<dim3(32, 4, 1), 256, 0, stream>>>(
      h1b, W2t, b2, nullptr, h2b, 2048, 256, 512, 512);
  // per-feature GEMV + bucketed minibatch-discrimination features
  k_feats<<<100, 1024, 0, stream>>>(h2b, T, feT);
  // final dot
  k_final<<<512, 256, 0, stream>>>(h2b, feT, Wf, bf, out);
}

// Round 5
// 126.962 us; speedup vs baseline: 1.2452x; 1.2452x over previous
//
#include <hip/hip_runtime.h>
#include <hip/hip_bf16.h>

#define LEAK 0.2f

typedef __attribute__((ext_vector_type(8))) short short8;
typedef __attribute__((ext_vector_type(4))) float f32x4;

// ---------- fused prep: x->bf16 convert ++ W1,W2,T transpose+convert ----------
// grid: [0,6144) convert, [6144,7680) W1t, [7680,7808) W2t, [7808,7840) Tt
__global__ __launch_bounds__(256) void k_prep(const float* __restrict__ x,
                                              __hip_bfloat16* __restrict__ xb,
                                              const float* __restrict__ W1,
                                              __hip_bfloat16* __restrict__ W1t,
                                              const float* __restrict__ W2,
                                              __hip_bfloat16* __restrict__ W2t,
                                              const float* __restrict__ T,
                                              __hip_bfloat16* __restrict__ Tt) {
  int b = blockIdx.x;
  int t = threadIdx.x;
  if (b < 6144) {
    int idx = b * 256 + t;
    float4 v = reinterpret_cast<const float4*>(x)[idx];
    union { ushort4 u; __hip_bfloat16 h[4]; } c;
    c.h[0] = __float2bfloat16(v.x);
    c.h[1] = __float2bfloat16(v.y);
    c.h[2] = __float2bfloat16(v.z);
    c.h[3] = __float2bfloat16(v.w);
    reinterpret_cast<ushort4*>(xb)[idx] = c.u;
    return;
  }
  __shared__ float tile[32][33];
  const float* W;
  __hip_bfloat16* Wt;
  int K, N, kblk, nblk;
  int b2 = b - 6144;
  if (b2 < 1536) {                  // W1: 3072x512 -> 512x3072
    W = W1; Wt = W1t; K = 3072; N = 512;
    kblk = b2 % 96; nblk = b2 / 96;
  } else if (b2 < 1664) {           // W2: 512x256 -> 256x512
    int b3 = b2 - 1536;
    W = W2; Wt = W2t; K = 512; N = 256;
    kblk = b3 % 16; nblk = b3 / 16;
  } else {                          // T: 256x100 -> 128x256 (zero-pad n>=100)
    int b4 = b2 - 1664;
    W = T; Wt = Tt; K = 256; N = 100;
    kblk = b4 % 8; nblk = b4 / 8;
  }
  int k0 = kblk * 32, n0 = nblk * 32;
  int tx = t & 31, ty = t >> 5;  // 32 x 8
#pragma unroll
  for (int r = 0; r < 4; ++r) {
    int n = n0 + tx;
    tile[ty + r * 8][tx] = (n < N) ? W[(long)(k0 + ty + r * 8) * N + n] : 0.f;
  }
  __syncthreads();
#pragma unroll
  for (int r = 0; r < 4; ++r)
    Wt[(long)(n0 + ty + r * 8) * K + k0 + tx] = __float2bfloat16(tile[tx][ty + r * 8]);
}

// ---------- bf16 MFMA GEMM, split-K, BK=64: Cp[z] = A[:,z*KSPL:+KSPL] @ Bt^T ----------
// A[M][K] bf16 row-major, Bt[N][K] bf16 row-major. Block tile 64x64, BK=64,
// 4 waves 2x2, wave 32x32 = 2x2 MFMA tiles of 16x16x32 (x2 k-halves).
// Register prefetch of next global tile overlaps MFMA+ds_read.
// TRANSP: store partial transposed (Cz[n][m], ld=ldO).
template <bool TRANSP>
__global__ __launch_bounds__(256) void k_gemm(const __hip_bfloat16* __restrict__ A,
                                              const __hip_bfloat16* __restrict__ Bt,
                                              float* __restrict__ Cp,
                                              int M, int N, int K, int KSPL, int ldO) {
  __shared__ __align__(16) __hip_bfloat16 As[64][72];  // +8 pad (2-way max = free)
  __shared__ __align__(16) __hip_bfloat16 Bs[64][72];
  int tid = threadIdx.x;
  int lane = tid & 63;
  int wv = tid >> 6;
  int wm = wv & 1, wn = wv >> 1;
  int quad = lane >> 4, l16 = lane & 15;
  long m0 = (long)blockIdx.x * 64, n0 = (long)blockIdx.y * 64;
  int srow = tid >> 2, scol = (tid & 3) * 16;
  int kStart = blockIdx.z * KSPL;
  const __hip_bfloat16* Ag = A + (m0 + srow) * K + kStart + scol;
  const __hip_bfloat16* Bg = Bt + (n0 + srow) * K + kStart + scol;

  int4 ra0 = *reinterpret_cast<const int4*>(Ag);
  int4 ra1 = *reinterpret_cast<const int4*>(Ag + 8);
  int4 rb0 = *reinterpret_cast<const int4*>(Bg);
  int4 rb1 = *reinterpret_cast<const int4*>(Bg + 8);

  f32x4 acc[2][2] = {};
  for (int kb = 0; kb < KSPL; kb += 64) {
    *reinterpret_cast<int4*>(&As[srow][scol]) = ra0;
    *reinterpret_cast<int4*>(&As[srow][scol + 8]) = ra1;
    *reinterpret_cast<int4*>(&Bs[srow][scol]) = rb0;
    *reinterpret_cast<int4*>(&Bs[srow][scol + 8]) = rb1;
    __syncthreads();
    if (kb + 64 < KSPL) {
      ra0 = *reinterpret_cast<const int4*>(Ag + kb + 64);
      ra1 = *reinterpret_cast<const int4*>(Ag + kb + 72);
      rb0 = *reinterpret_cast<const int4*>(Bg + kb + 64);
      rb1 = *reinterpret_cast<const int4*>(Bg + kb + 72);
    }
#pragma unroll
    for (int half = 0; half < 2; ++half) {
      short8 af[2], bfr[2];
#pragma unroll
      for (int t = 0; t < 2; ++t) {
        af[t]  = *reinterpret_cast<const short8*>(&As[wm * 32 + t * 16 + l16][half * 32 + quad * 8]);
        bfr[t] = *reinterpret_cast<const short8*>(&Bs[wn * 32 + t * 16 + l16][half * 32 + quad * 8]);
      }
#pragma unroll
      for (int tm = 0; tm < 2; ++tm)
#pragma unroll
        for (int tn = 0; tn < 2; ++tn)
          acc[tm][tn] =
              __builtin_amdgcn_mfma_f32_16x16x32_bf16(af[tm], bfr[tn], acc[tm][tn], 0, 0, 0);
    }
    __syncthreads();
  }

  float* Cz = Cp + (long)blockIdx.z * M * N;
#pragma unroll
  for (int tm = 0; tm < 2; ++tm)
#pragma unroll
    for (int tn = 0; tn < 2; ++tn)
#pragma unroll
      for (int r = 0; r < 4; ++r) {
        long gm = m0 + wm * 32 + tm * 16 + quad * 4 + r;  // row = quad*4 + reg
        long gn = n0 + wn * 32 + tn * 16 + l16;           // col = lane&15
        if (TRANSP) Cz[gn * ldO + gm] = acc[tm][tn][r];
        else        Cz[gm * ldO + gn] = acc[tm][tn][r];
      }
}

// ---------- combine NZ partials + bias + leakyrelu -> bf16 (+ optional fp32) ----------
template <int NZ, bool OUTF>
__global__ __launch_bounds__(256) void k_comb(const float* __restrict__ P,
                                              const float* __restrict__ bias,
                                              float* __restrict__ Of,
                                              __hip_bfloat16* __restrict__ Ob,
                                              int total4, int nmask) {
  int idx = blockIdx.x * 256 + threadIdx.x;
  if (idx >= total4) return;
  float4 v = reinterpret_cast<const float4*>(P)[idx];
#pragma unroll
  for (int z = 1; z < NZ; ++z) {
    float4 a = reinterpret_cast<const float4*>(P + (long)z * total4 * 4)[idx];
    v.x += a.x; v.y += a.y; v.z += a.z; v.w += a.w;
  }
  int col = (idx * 4) & nmask;
  float4 bs = *reinterpret_cast<const float4*>(bias + col);
  v.x += bs.x; v.y += bs.y; v.z += bs.z; v.w += bs.w;
  v.x = v.x > 0.f ? v.x : LEAK * v.x;
  v.y = v.y > 0.f ? v.y : LEAK * v.y;
  v.z = v.z > 0.f ? v.z : LEAK * v.z;
  v.w = v.w > 0.f ? v.w : LEAK * v.w;
  if (OUTF) reinterpret_cast<float4*>(Of)[idx] = v;
  union { ushort4 u; __hip_bfloat16 h[4]; } c;
  c.h[0] = __float2bfloat16(v.x);
  c.h[1] = __float2bfloat16(v.y);
  c.h[2] = __float2bfloat16(v.z);
  c.h[3] = __float2bfloat16(v.w);
  reinterpret_cast<ushort4*>(Ob)[idx] = c.u;
}

// ---------- bucketed minibatch-discrimination features, O(B) ----------
// feats[i] = sum_j e^{-|mi-mj|}. 256 value buckets: lower buckets contribute
// n_i*sum(p_j), upper p_i*sum(n_j) (exact by monotonicity), own bucket exact.
// p,n centered at mid, args clamped +-60 (clamp error < e^-70).
__global__ __launch_bounds__(1024) void k_bucketfeats(const float* __restrict__ mTz,
                                                      float* __restrict__ featsT) {
  __shared__ float sP[2048], sN[2048];
  __shared__ float Sp[2048], Sn[2048];
  __shared__ int Smeta[2048];
  __shared__ short sB[2048];
  __shared__ int cnt[256], bstart[256], bcur[256];
  __shared__ float bsP[256], bsN[256], Pbel[256], Nab[256];
  __shared__ float wred[32];
  __shared__ float sMin, sMax;
  int f = blockIdx.x;
  int t = threadIdx.x;
  int lane = t & 63, wv = t >> 6;
  const long FS = 2048L * 128;
  const float* row = mTz + (long)f * 2048;

  float m[2];
  float lmin = 3.4e38f, lmax = -3.4e38f;
#pragma unroll
  for (int r = 0; r < 2; ++r) {
    int e = t + r * 1024;
    float v = row[e] + row[FS + e] + row[2 * FS + e] + row[3 * FS + e];
    m[r] = v;
    lmin = fminf(lmin, v);
    lmax = fmaxf(lmax, v);
  }
#pragma unroll
  for (int d = 32; d; d >>= 1) {
    lmin = fminf(lmin, __shfl_down(lmin, d));
    lmax = fmaxf(lmax, __shfl_down(lmax, d));
  }
  if (lane == 0) { wred[wv] = lmin; wred[16 + wv] = lmax; }
  if (t < 256) cnt[t] = 0;
  __syncthreads();
  if (t == 0) {
    float a = wred[0], b = wred[16];
    for (int i = 1; i < 16; ++i) { a = fminf(a, wred[i]); b = fmaxf(b, wred[16 + i]); }
    sMin = a; sMax = b;
  }
  __syncthreads();
  float mn = sMin, mx = sMax;
  float rge = mx - mn;
  float scale = (rge > 1e-20f) ? 255.0f / rge : 0.f;
  float mid = 0.5f * (mn + mx);
#pragma unroll
  for (int r = 0; r < 2; ++r) {
    int e = t + r * 1024;
    float v = m[r];
    int b = (int)((v - mn) * scale);
    b = b < 255 ? b : 255;
    float arg = fminf(fmaxf(v - mid, -60.f), 60.f);
    sP[e] = __expf(arg);
    sN[e] = __expf(-arg);
    sB[e] = (short)b;
    atomicAdd(&cnt[b], 1);
  }
  __syncthreads();
  if (wv == 0) {  // exclusive prefix of cnt (4 bins/lane + wave scan)
    int b4 = lane * 4;
    int c0 = cnt[b4], c1 = cnt[b4 + 1], c2 = cnt[b4 + 2], c3 = cnt[b4 + 3];
    int tot = c0 + c1 + c2 + c3;
    int inc = tot;
#pragma unroll
    for (int d = 1; d < 64; d <<= 1) {
      int y = __shfl_up(inc, d);
      if (lane >= d) inc += y;
    }
    int run = inc - tot;
    bstart[b4] = run; bcur[b4] = run; run += c0;
    bstart[b4 + 1] = run; bcur[b4 + 1] = run; run += c1;
    bstart[b4 + 2] = run; bcur[b4 + 2] = run; run += c2;
    bstart[b4 + 3] = run; bcur[b4 + 3] = run;
  }
  __syncthreads();
#pragma unroll
  for (int r = 0; r < 2; ++r) {  // scatter into bucket order
    int e = t + r * 1024;
    int b = sB[e];
    int slot = atomicAdd(&bcur[b], 1);
    Sp[slot] = sP[e];
    Sn[slot] = sN[e];
    Smeta[slot] = (b << 16) | e;
  }
  __syncthreads();
  if (t < 256) {  // per-bucket sums
    int s0 = bstart[t], s1 = s0 + cnt[t];
    float ap = 0.f, an = 0.f;
    for (int q = s0; q < s1; ++q) { ap += Sp[q]; an += Sn[q]; }
    bsP[t] = ap; bsN[t] = an;
  }
  __syncthreads();
  if (wv == 0) {  // bucket-level exclusive prefix(P) / suffix(N)
    int b4 = lane * 4;
    float p0 = bsP[b4], p1 = bsP[b4 + 1], p2 = bsP[b4 + 2], p3 = bsP[b4 + 3];
    float n0 = bsN[b4], n1 = bsN[b4 + 1], n2 = bsN[b4 + 2], n3 = bsN[b4 + 3];
    float tp = p0 + p1 + p2 + p3, tn = n0 + n1 + n2 + n3;
    float ip = tp, in_ = tn;
#pragma unroll
    for (int d = 1; d < 64; d <<= 1) {
      float yp = __shfl_up(ip, d);
      float yn = __shfl_up(in_, d);
      if (lane >= d) { ip += yp; in_ += yn; }
    }
    float totn = __shfl(in_, 63);
    float runp = ip - tp;
    float runn = in_ - tn;
    Pbel[b4] = runp; Nab[b4] = totn - runn - n0; runp += p0; runn += n0;
    Pbel[b4 + 1] = runp; Nab[b4 + 1] = totn - runn - n1; runp += p1; runn += n1;
    Pbel[b4 + 2] = runp; Nab[b4 + 2] = totn - runn - n2; runp += p2; runn += n2;
    Pbel[b4 + 3] = runp; Nab[b4 + 3] = totn - runn - n3;
  }
  __syncthreads();
#pragma unroll
  for (int r = 0; r < 2; ++r) {
    int s = t + r * 1024;
    int meta = Smeta[s];
    int b = meta >> 16;
    int idx = meta & 0xFFFF;
    float p = Sp[s], n = Sn[s];
    float acc = n * Pbel[b] + p * Nab[b];
    int q0 = bstart[b], q1 = q0 + cnt[b];
    for (int q = q0; q < q1; ++q) acc += fminf(p * Sn[q], n * Sp[q]);
    featsT[(long)f * 2048 + idx] = acc;
  }
}

// ---------- final: out[i] = h2[i,:].Wf[0:256] + featsT[:,i].Wf[256:356] + bf ----------
__global__ __launch_bounds__(256) void k_final(const float* __restrict__ h2f,
                                               const float* __restrict__ featsT,
                                               const float* __restrict__ Wf,
                                               const float* __restrict__ bfp,
                                               float* __restrict__ out) {
  int wv = threadIdx.x >> 6, lane = threadIdx.x & 63;
  long i = (long)blockIdx.x * 4 + wv;
  const float* hrow = h2f + i * 256;
  float s = 0.f;
#pragma unroll
  for (int c = lane; c < 256; c += 64) s += hrow[c] * Wf[c];
  for (int f = lane; f < 100; f += 64) s += featsT[(long)f * 2048 + i] * Wf[256 + f];
#pragma unroll
  for (int off = 32; off; off >>= 1) s += __shfl_down(s, off);
  if (lane == 0) out[i] = s + bfp[0];
}

extern "C" void kernel_launch(void* const* d_in, const int* in_sizes, int n_in,
                              void* d_out, int out_size, void* d_ws, size_t ws_size,
                              hipStream_t stream) {
  const float* x  = (const float*)d_in[0];
  const float* W1 = (const float*)d_in[1];
  const float* b1 = (const float*)d_in[2];
  const float* W2 = (const float*)d_in[3];
  const float* b2 = (const float*)d_in[4];
  const float* T  = (const float*)d_in[5];
  const float* Wf = (const float*)d_in[6];
  const float* bf = (const float*)d_in[7];
  float* out = (float*)d_out;

  char* w = (char*)d_ws;
  auto alloc = [&](size_t b) { char* p = w; w += (b + 255) & ~(size_t)255; return p; };
  __hip_bfloat16* xb  = (__hip_bfloat16*)alloc(2048L * 3072 * 2);  // 12 MB
  __hip_bfloat16* W1t = (__hip_bfloat16*)alloc(512L * 3072 * 2);   // 3 MB
  __hip_bfloat16* W2t = (__hip_bfloat16*)alloc(256L * 512 * 2);
  __hip_bfloat16* Tt  = (__hip_bfloat16*)alloc(128L * 256 * 2);
  __hip_bfloat16* h1b = (__hip_bfloat16*)alloc(2048L * 512 * 2);   // 2 MB
  float*          h2f = (float*)alloc(2048L * 256 * 4);            // 2 MB
  __hip_bfloat16* h2b = (__hip_bfloat16*)alloc(2048L * 256 * 2);   // 1 MB
  float*          feT = (float*)alloc(100L * 2048 * 4);            // 0.8 MB
  float*          P1  = (float*)alloc(3L * 2048 * 512 * 4);        // 12 MB
  float*          P2  = (float*)alloc(2L * 2048 * 256 * 4);        // 4 MB
  float*          P3  = (float*)alloc(4L * 2048 * 128 * 4);        // 4 MB

  // prep: x->bf16 (6144) + W1t (1536) + W2t (128) + Tt (32)
  k_prep<<<7840, 256, 0, stream>>>(x, xb, W1, W1t, W2, W2t, T, Tt);
  // h1 = leakyrelu(x @ W1 + b1): split-K=3 (768 blocks, 3/CU), BK=64
  k_gemm<false><<<dim3(32, 8, 3), 256, 0, stream>>>(xb, W1t, P1, 2048, 512, 3072, 1024, 512);
  k_comb<3, false><<<1024, 256, 0, stream>>>(P1, b1, nullptr, h1b, 262144, 511);
  // h2 = leakyrelu(h1 @ W2 + b2): split-K=2
  k_gemm<false><<<dim3(32, 4, 2), 256, 0, stream>>>(h1b, W2t, P2, 2048, 256, 512, 256, 256);
  k_comb<2, true><<<512, 256, 0, stream>>>(P2, b2, h2f, h2b, 131072, 255);
  // m = h2 @ T: split-K=4, transposed partial stores (mTz[128][2048] per z)
  k_gemm<true><<<dim3(32, 2, 4), 256, 0, stream>>>(h2b, Tt, P3, 2048, 128, 256, 64, 2048);
  // minibatch-discrimination features via value bucketing (O(B))
  k_bucketfeats<<<100, 1024, 0, stream>>>(P3, feT);
  // final dot
  k_final<<<512, 256, 0, stream>>>(h2f, feT, Wf, bf, out);
}